// Round 1
// baseline (567.750 us; speedup 1.0000x reference)
//
#include <hip/hip_runtime.h>
#include <hip/hip_bf16.h>

#define B_SZ   16384
#define IN_DIM 4096
#define H1D    128
#define H2D    64
#define LAT    32

typedef _Float16 half8 __attribute__((ext_vector_type(8)));
typedef _Float16 half4 __attribute__((ext_vector_type(4)));
typedef float float4v __attribute__((ext_vector_type(4)));

// ---- workspace layout (bytes) ----
#define WS_W2T  1048576
#define WS_W3T  1064960
#define WS_WDT  1069056
#define WS_B3O  1331200

// -------- prepass: transpose + fp32->fp16 convert weights, fold qparams into b3 --------
__global__ __launch_bounds__(256) void prep_kernel(
    const float* __restrict__ W1, const float* __restrict__ W2,
    const float* __restrict__ W3, const float* __restrict__ Wd,
    const float* __restrict__ b3, const float* __restrict__ qp,
    _Float16* __restrict__ W1t, _Float16* __restrict__ W2t,
    _Float16* __restrict__ W3t, _Float16* __restrict__ Wdt,
    float* __restrict__ b3off)
{
    int t = blockIdx.x * 256 + threadIdx.x;
    if (t < IN_DIM * H1D) {              // W1[k][n] -> W1t[n][k]
        int k = t >> 7, n = t & 127;
        W1t[n * IN_DIM + k] = (_Float16)W1[t];
    }
    if (t < LAT * IN_DIM) {              // Wd[k][n] -> Wdt[n][k]
        int k = t >> 12, n = t & 4095;
        Wdt[n * LAT + k] = (_Float16)Wd[t];
    }
    if (t < H1D * H2D) {                 // W2[k][n] -> W2t[n][k]
        int k = t >> 6, n = t & 63;
        W2t[n * H1D + k] = (_Float16)W2[t];
    }
    if (t < H2D * LAT) {                 // W3[k][n] -> W3t[n][k]
        int k = t >> 5, n = t & 31;
        W3t[n * H2D + k] = (_Float16)W3[t];
    }
    if (t < LAT) {
        float s = b3[t];
        #pragma unroll
        for (int r = 0; r < 6; ++r) s += qp[r * LAT + t];
        b3off[t] = s;
    }
}

static __device__ __forceinline__ half8 cvt8(float4v v0, float4v v1) {
    half8 h;
    h[0] = (_Float16)v0[0]; h[1] = (_Float16)v0[1];
    h[2] = (_Float16)v0[2]; h[3] = (_Float16)v0[3];
    h[4] = (_Float16)v1[0]; h[5] = (_Float16)v1[1];
    h[6] = (_Float16)v1[2]; h[7] = (_Float16)v1[3];
    return h;
}

// -------- fused kernel: full forward for 32 rows per block --------
// 512 blocks x 256 threads.
// Phase A: layer1 (K-split across 4 waves, barrier-free K-loop), LDS reduce.
// Phase B: layer2, layer3+cos -> q[32][32] fp16 kept in LDS (never leaves chip).
// Phase C: decode with SWAPPED mfma operands (A=Wd^T frag -> output-col axis in
//          regs) so each lane stores 4 consecutive floats of one output row:
//          direct global_store_dwordx4, no LDS transpose needed.
__global__ __launch_bounds__(256, 2) void fused_kernel(
    const float* __restrict__ x,
    const _Float16* __restrict__ W1t, const _Float16* __restrict__ W2t,
    const _Float16* __restrict__ W3t, const _Float16* __restrict__ Wdt,
    const float* __restrict__ b1, const float* __restrict__ b2,
    const float* __restrict__ b3off, const float* __restrict__ bd,
    float* __restrict__ out)
{
    __shared__ alignas(16) float part[4 * 32 * 132];   // 67584 B, K-split partials
    __shared__ alignas(16) _Float16 h1s[32 * 136];     // 8704 B
    _Float16* h2s = (_Float16*)part;                   // [32][72], aliases part (dead by then)
    _Float16* qs  = h1s;                               // [32][40],  aliases h1s (dead by then)

    const int tid  = threadIdx.x;
    const int lane = tid & 63;
    const int w    = tid >> 6;        // 0..3  = K-quarter / col-quarter
    const int l15  = lane & 15;
    const int quad = lane >> 4;       // 0..3
    const int rb0  = blockIdx.x * 32;

    // ---- phase A: layer 1, acc[2 row-frags][8 col-frags], K-chunk = 1024 per wave ----
    float4v acc[2][8];
    #pragma unroll
    for (int mg = 0; mg < 2; ++mg)
        #pragma unroll
        for (int ct = 0; ct < 8; ++ct)
            acc[mg][ct] = (float4v){0.f, 0.f, 0.f, 0.f};

    const float* xp0 = x + (size_t)(rb0 + l15) * IN_DIM + w * 1024 + quad * 8;
    const float* xp1 = xp0 + 16 * IN_DIM;
    const _Float16* wp[8];
    #pragma unroll
    for (int ct = 0; ct < 8; ++ct)
        wp[ct] = W1t + (size_t)(ct * 16 + l15) * IN_DIM + w * 1024 + quad * 8;

    #pragma unroll 2
    for (int kk = 0; kk < 32; ++kk) {
        const int ko = kk * 32;
        // non-temporal: x is streamed exactly once; keep weights resident in L2
        float4v x00 = __builtin_nontemporal_load((const float4v*)(xp0 + ko));
        float4v x01 = __builtin_nontemporal_load((const float4v*)(xp0 + ko + 4));
        float4v x10 = __builtin_nontemporal_load((const float4v*)(xp1 + ko));
        float4v x11 = __builtin_nontemporal_load((const float4v*)(xp1 + ko + 4));
        half8 a0 = cvt8(x00, x01);
        half8 a1 = cvt8(x10, x11);
        #pragma unroll
        for (int ct = 0; ct < 8; ++ct) {
            half8 b = *(const half8*)(wp[ct] + ko);
            acc[0][ct] = __builtin_amdgcn_mfma_f32_16x16x32_f16(a0, b, acc[0][ct], 0, 0, 0);
            acc[1][ct] = __builtin_amdgcn_mfma_f32_16x16x32_f16(a1, b, acc[1][ct], 0, 0, 0);
        }
    }

    // write per-wave partials to LDS
    {
        float* pw = part + w * (32 * 132);
        #pragma unroll
        for (int mg = 0; mg < 2; ++mg)
            #pragma unroll
            for (int ct = 0; ct < 8; ++ct)
                #pragma unroll
                for (int r = 0; r < 4; ++r)
                    pw[(mg * 16 + quad * 4 + r) * 132 + ct * 16 + l15] = acc[mg][ct][r];
    }
    __syncthreads();

    // reduce 4 partials + bias + relu -> h1s fp16 [32][136]
    #pragma unroll
    for (int i = 0; i < 4; ++i) {
        int chunk = tid * 4 + i;          // 0..1023 float4 chunks of [32][128]
        int row = chunk >> 5;
        int c4  = chunk & 31;
        const float* p = part + row * 132 + c4 * 4;
        float4v s = *(const float4v*)(p)
                  + *(const float4v*)(p + 32 * 132)
                  + *(const float4v*)(p + 2 * 32 * 132)
                  + *(const float4v*)(p + 3 * 32 * 132);
        float4v bb = *(const float4v*)(b1 + c4 * 4);
        s = s + bb;
        half4 h;
        h[0] = (_Float16)(s[0] > 0.f ? s[0] : 0.f);
        h[1] = (_Float16)(s[1] > 0.f ? s[1] : 0.f);
        h[2] = (_Float16)(s[2] > 0.f ? s[2] : 0.f);
        h[3] = (_Float16)(s[3] > 0.f ? s[3] : 0.f);
        *(half4*)(h1s + row * 136 + c4 * 4) = h;
    }
    __syncthreads();

    // ---- phase B: layer 2: h2[32][64] = relu(h1 @ W2 + b2); wave w -> cols w*16..+15 ----
    {
        float bv2 = b2[w * 16 + l15];
        float4v a2[2] = {(float4v){bv2, bv2, bv2, bv2}, (float4v){bv2, bv2, bv2, bv2}};
        #pragma unroll
        for (int kk = 0; kk < 4; ++kk) {
            half8 b = *(const half8*)(W2t + (w * 16 + l15) * H1D + kk * 32 + quad * 8);
            half8 a0 = *(const half8*)(h1s + l15 * 136 + kk * 32 + quad * 8);
            half8 a1 = *(const half8*)(h1s + (16 + l15) * 136 + kk * 32 + quad * 8);
            a2[0] = __builtin_amdgcn_mfma_f32_16x16x32_f16(a0, b, a2[0], 0, 0, 0);
            a2[1] = __builtin_amdgcn_mfma_f32_16x16x32_f16(a1, b, a2[1], 0, 0, 0);
        }
        __syncthreads();   // h2s aliases part; ensure reduction reads are done
        #pragma unroll
        for (int mg = 0; mg < 2; ++mg)
            #pragma unroll
            for (int r = 0; r < 4; ++r) {
                float v = a2[mg][r];
                h2s[(mg * 16 + quad * 4 + r) * 72 + w * 16 + l15] = (_Float16)(v > 0.f ? v : 0.f);
            }
    }
    __syncthreads();       // also guarantees all h1s reads done before qs overwrite

    // ---- layer 3 + cos -> qs[32][40] fp16 in LDS; wave w -> row-group w>>1, col-group w&1 ----
    {
        const int mg3 = w >> 1;
        const int ct3 = w & 1;
        const int c3  = ct3 * 16 + l15;
        float bv3 = b3off[c3];
        float4v a3 = (float4v){bv3, bv3, bv3, bv3};
        #pragma unroll
        for (int kk = 0; kk < 2; ++kk) {
            half8 a = *(const half8*)(h2s + (mg3 * 16 + l15) * 72 + kk * 32 + quad * 8);
            half8 b = *(const half8*)(W3t + c3 * H2D + kk * 32 + quad * 8);
            a3 = __builtin_amdgcn_mfma_f32_16x16x32_f16(a, b, a3, 0, 0, 0);
        }
        #pragma unroll
        for (int r = 0; r < 4; ++r)
            qs[(mg3 * 16 + quad * 4 + r) * 40 + c3] = (_Float16)cosf(a3[r]);
    }
    __syncthreads();

    // ---- phase C: decode out[32][4096] = q @ Wd + bd; wave w -> cols [w*1024, +1024) ----
    // Swapped operands: A-frag = Wd^T rows (output cols), B-frag = q rows (output rows).
    // D layout: reg axis (quad*4+r) = output COLUMN -> each lane's 4 regs are 4
    // consecutive floats of one output row => dwordx4 store, 16 rows x 64 B / instr.
    {
        const int wbase = w * 1024;
        half8 bq0 = *(const half8*)(qs + l15 * 40 + quad * 8);         // q rows 0..15
        half8 bq1 = *(const half8*)(qs + (16 + l15) * 40 + quad * 8);  // q rows 16..31
        const _Float16* wdp = Wdt + (size_t)(wbase + l15) * LAT + quad * 8;
        const float* bdp = bd + wbase + quad * 4;
        float* op0 = out + (size_t)(rb0 + l15) * IN_DIM + wbase + quad * 4;
        float* op1 = op0 + (size_t)16 * IN_DIM;
        #pragma unroll 2
        for (int ct = 0; ct < 64; ++ct) {
            half8 aw = *(const half8*)(wdp + ct * 16 * LAT);
            float4v bias = *(const float4v*)(bdp + ct * 16);
            float4v o0 = __builtin_amdgcn_mfma_f32_16x16x32_f16(aw, bq0, bias, 0, 0, 0);
            float4v o1 = __builtin_amdgcn_mfma_f32_16x16x32_f16(aw, bq1, bias, 0, 0, 0);
            __builtin_nontemporal_store(o0, (float4v*)(op0 + ct * 16));
            __builtin_nontemporal_store(o1, (float4v*)(op1 + ct * 16));
        }
    }
}

extern "C" void kernel_launch(void* const* d_in, const int* in_sizes, int n_in,
                              void* d_out, int out_size, void* d_ws, size_t ws_size,
                              hipStream_t stream)
{
    const float* x  = (const float*)d_in[0];
    const float* W1 = (const float*)d_in[1];
    const float* b1 = (const float*)d_in[2];
    const float* W2 = (const float*)d_in[3];
    const float* b2 = (const float*)d_in[4];
    const float* W3 = (const float*)d_in[5];
    const float* b3 = (const float*)d_in[6];
    const float* qp = (const float*)d_in[7];
    const float* Wd = (const float*)d_in[8];
    const float* bd = (const float*)d_in[9];
    float* out = (float*)d_out;

    char* ws = (char*)d_ws;
    _Float16* W1t = (_Float16*)(ws);
    _Float16* W2t = (_Float16*)(ws + WS_W2T);
    _Float16* W3t = (_Float16*)(ws + WS_W3T);
    _Float16* Wdt = (_Float16*)(ws + WS_WDT);
    float*    b3o = (float*)(ws + WS_B3O);

    prep_kernel<<<2048, 256, 0, stream>>>(W1, W2, W3, Wd, b3, qp, W1t, W2t, W3t, Wdt, b3o);
    fused_kernel<<<512, 256, 0, stream>>>(x, W1t, W2t, W3t, Wdt, b1, b2, b3o, bd, out);
}